// Round 10
// baseline (410.933 us; speedup 1.0000x reference)
//
#include <hip/hip_runtime.h>
#include <hip/hip_bf16.h>

#define N_NODES 50000
#define N_EDGES 800000
#define NBK 391          // ceil(50000/128) row buckets of 128 rows
#define BCAP 2560        // slab capacity per bucket (mean 2048 + 11 sigma)

static inline int cdiv(int a, int b) { return (a + b - 1) / b; }

typedef __attribute__((ext_vector_type(8))) short short8;
typedef __attribute__((ext_vector_type(4))) float f32x4;

__device__ __forceinline__ float b2f(unsigned short u) {
    union { unsigned int i; float f; } c;
    c.i = ((unsigned int)u) << 16;
    return c.f;
}
__device__ __forceinline__ unsigned short f2bb(float f) {
    __hip_bfloat16 h = __float2bfloat16(f);
    return *(unsigned short*)&h;
}

// ---------------- CSR build ----------------

__global__ __launch_bounds__(256)
void binA_kernel(const int* __restrict__ row, const int* __restrict__ col,
                 const float* __restrict__ vals, int* __restrict__ bcursor,
                 int2* __restrict__ tmp, int E) {
    __shared__ int hist[NBK];
    __shared__ int base[NBK];
    const int CH = 4096;
    int e0 = blockIdx.x * CH;
    for (int i = threadIdx.x; i < NBK; i += 256) hist[i] = 0;
    __syncthreads();
    for (int i = threadIdx.x; i < CH; i += 256) {
        int e = e0 + i;
        if (e < E) atomicAdd(&hist[row[e] >> 7], 1);
    }
    __syncthreads();
    for (int i = threadIdx.x; i < NBK; i += 256) {
        int c = hist[i];
        base[i] = (c > 0) ? atomicAdd(&bcursor[i], c) : 0;
        hist[i] = 0;
    }
    __syncthreads();
    for (int i = threadIdx.x; i < CH; i += 256) {
        int e = e0 + i;
        if (e < E) {
            int r = row[e];
            int b = r >> 7;
            int rk = atomicAdd(&hist[b], 1);
            tmp[base[b] + rk] = make_int2(((r & 127) << 16) | col[e],
                                          __float_as_int(vals[e]));
        }
    }
}

__global__ __launch_bounds__(512)
void bscan_kernel(const int* __restrict__ bcursor, int* __restrict__ bbase) {
    __shared__ int s[512];
    int t = threadIdx.x;
    int v = (t < NBK) ? (bcursor[t] - t * BCAP) : 0;
    s[t] = v;
    __syncthreads();
    for (int off = 1; off < 512; off <<= 1) {
        int u = (t >= off) ? s[t - off] : 0;
        __syncthreads();
        s[t] += u;
        __syncthreads();
    }
    if (t < NBK) bbase[t] = s[t] - v;
    if (t == NBK - 1) bbase[NBK] = s[t];
}

__global__ __launch_bounds__(256)
void binB_kernel(const int2* __restrict__ tmp, const int* __restrict__ bcursor,
                 const int* __restrict__ bbase, int* __restrict__ row_ptr,
                 int2* __restrict__ epack, int N) {
    int b = blockIdx.x;
    int r0 = b << 7;
    int nr = N - r0; if (nr > 128) nr = 128;
    __shared__ int cnt[128];
    __shared__ int cur[128];
    int t = threadIdx.x;
    if (t < 128) cnt[t] = 0;
    __syncthreads();
    int slab = b * BCAP;
    int send = bcursor[b];
    int obase = bbase[b];
    for (int i = slab + t; i < send; i += 256)
        atomicAdd(&cnt[tmp[i].x >> 16], 1);
    __syncthreads();
    if (t < 128) cur[t] = cnt[t];
    __syncthreads();
    for (int off = 1; off < 128; off <<= 1) {
        int u = (t >= off && t < 128) ? cur[t - off] : 0;
        __syncthreads();
        if (t < 128) cur[t] += u;
        __syncthreads();
    }
    if (t < 128) {
        int ex = cur[t] - cnt[t];
        int pos = obase + ex;
        cur[t] = pos;
        if (t < nr) row_ptr[r0 + t] = pos;
    }
    if (b == NBK - 1 && t == 128) row_ptr[N] = bbase[NBK];
    __syncthreads();
    for (int i = slab + t; i < send; i += 256) {
        int2 v = tmp[i];
        int rl = v.x >> 16;
        int c = v.x & 0xffff;
        int pos = atomicAdd(&cur[rl], 1);
        epack[pos] = make_int2(c, v.y);
    }
}

// ---------------- prep: weight packing + bucket-cursor init ----------------

__device__ __forceinline__ void pack_one(const float* __restrict__ W,
                                         __hip_bfloat16* __restrict__ out,
                                         int K, int N, int t) {
    int lane = t & 63;
    int kc = (t >> 6) % (K / 32);
    int nt = (t >> 6) / (K / 32);
    int kbase = kc * 32 + (lane >> 4) * 8;
    int col = nt * 16 + (lane & 15);
    __hip_bfloat16* dst = out + (size_t)t * 8;
#pragma unroll
    for (int j = 0; j < 8; ++j)
        dst[j] = __float2bfloat16(W[(size_t)(kbase + j) * N + col]);
}

__global__ __launch_bounds__(256)
void prep_kernel(const float* __restrict__ W1, const float* __restrict__ W2,
                 const float* __restrict__ W3, const float* __restrict__ fcW1,
                 const float* __restrict__ fcW2,
                 __hip_bfloat16* __restrict__ pW1, __hip_bfloat16* __restrict__ pW2,
                 __hip_bfloat16* __restrict__ pW3, __hip_bfloat16* __restrict__ pfcW1,
                 __hip_bfloat16* __restrict__ pfcW2, int* __restrict__ bcursor) {
    int b = blockIdx.x;
    if (b < 8)       pack_one(W1,  pW1,  128, 128, b * 256 + threadIdx.x);
    else if (b < 16) pack_one(W2,  pW2,  128, 128, (b - 8) * 256 + threadIdx.x);
    else if (b < 24) pack_one(W3,  pW3,  128, 128, (b - 16) * 256 + threadIdx.x);
    else if (b < 48) pack_one(fcW1, pfcW1, 384, 128, (b - 24) * 256 + threadIdx.x);
    else if (b < 52) pack_one(fcW2, pfcW2, 128, 64, (b - 48) * 256 + threadIdx.x);
    else {
        int t = (b - 52) * 256 + threadIdx.x;
        if (t < NBK) bcursor[t] = t * BCAP;
    }
}

// ---------------- K1: gemm1, fp32 A staged+converted ----------------
__global__ __launch_bounds__(256, 3)
void gemm1_kernel(const float* __restrict__ A,
                  const __hip_bfloat16* __restrict__ pW,
                  __hip_bfloat16* __restrict__ C, int M) {
    __shared__ unsigned short As[64][136];
    const int tid = threadIdx.x;
    const int wave = tid >> 6;
    const int lane = tid & 63;
    const int ln15 = lane & 15;
    const int quad = lane >> 4;
    const int m0 = blockIdx.x * 64;
    const int ntw = wave * 2;

    f32x4 acc[4][2];
#pragma unroll
    for (int s = 0; s < 4; ++s)
#pragma unroll
        for (int h = 0; h < 2; ++h) acc[s][h] = (f32x4){0.f, 0.f, 0.f, 0.f};

#pragma unroll
    for (int i = 0; i < 4; ++i) {
        int idx = tid + i * 256;
        int r = idx >> 4;
        int c8 = (idx & 15) * 8;
        uint4 pk = {0, 0, 0, 0};
        if (m0 + r < M) {
            const float* src = &A[(size_t)(m0 + r) * 128 + c8];
            float4 a = *(const float4*)src;
            float4 bq = *(const float4*)(src + 4);
            pk.x = f2bb(a.x) | ((unsigned int)f2bb(a.y) << 16);
            pk.y = f2bb(a.z) | ((unsigned int)f2bb(a.w) << 16);
            pk.z = f2bb(bq.x) | ((unsigned int)f2bb(bq.y) << 16);
            pk.w = f2bb(bq.z) | ((unsigned int)f2bb(bq.w) << 16);
        }
        *(uint4*)&As[r][c8] = pk;
    }
    __syncthreads();
#pragma unroll
    for (int kc = 0; kc < 4; ++kc) {
        short8 af[4];
#pragma unroll
        for (int s = 0; s < 4; ++s)
            af[s] = *(const short8*)&As[s * 16 + ln15][kc * 32 + quad * 8];
        short8 bf[2];
#pragma unroll
        for (int h = 0; h < 2; ++h)
            bf[h] = *(const short8*)&pW[((size_t)((ntw + h) * 4 + kc) * 64 + lane) * 8];
#pragma unroll
        for (int s = 0; s < 4; ++s)
#pragma unroll
            for (int h = 0; h < 2; ++h)
                acc[s][h] = __builtin_amdgcn_mfma_f32_16x16x32_bf16(
                    af[s], bf[h], acc[s][h], 0, 0, 0);
    }

#pragma unroll
    for (int s = 0; s < 4; ++s)
#pragma unroll
        for (int h = 0; h < 2; ++h) {
            int col = (ntw + h) * 16 + ln15;
#pragma unroll
            for (int r = 0; r < 4; ++r) {
                int row = m0 + s * 16 + quad * 4 + r;
                if (row < M)
                    C[(size_t)row * 128 + col] = __float2bfloat16(acc[s][h][r]);
            }
        }
}

// ---------------- aggregation helper: one node per wave, 128 dims ----------------
__device__ __forceinline__ void agg_node(const int* __restrict__ row_ptr,
                                         const long long* __restrict__ ep,
                                         const __hip_bfloat16* __restrict__ support,
                                         int node, int lane, float& ax, float& ay) {
    int pstart = row_ptr[node], pend = row_ptr[node + 1];
    int p = pstart;
    for (; p + 4 <= pend; p += 4) {
        long long v0 = __builtin_nontemporal_load(&ep[p]);
        long long v1 = __builtin_nontemporal_load(&ep[p + 1]);
        long long v2 = __builtin_nontemporal_load(&ep[p + 2]);
        long long v3 = __builtin_nontemporal_load(&ep[p + 3]);
        ushort2 u0 = *(const ushort2*)&support[(size_t)(unsigned int)(v0 & 0xffffffff) * 128 + lane * 2];
        ushort2 u1 = *(const ushort2*)&support[(size_t)(unsigned int)(v1 & 0xffffffff) * 128 + lane * 2];
        ushort2 u2 = *(const ushort2*)&support[(size_t)(unsigned int)(v2 & 0xffffffff) * 128 + lane * 2];
        ushort2 u3 = *(const ushort2*)&support[(size_t)(unsigned int)(v3 & 0xffffffff) * 128 + lane * 2];
        float f0 = __int_as_float((int)(v0 >> 32));
        float f1 = __int_as_float((int)(v1 >> 32));
        float f2 = __int_as_float((int)(v2 >> 32));
        float f3 = __int_as_float((int)(v3 >> 32));
        ax += f0 * b2f(u0.x) + f1 * b2f(u1.x) + f2 * b2f(u2.x) + f3 * b2f(u3.x);
        ay += f0 * b2f(u0.y) + f1 * b2f(u1.y) + f2 * b2f(u2.y) + f3 * b2f(u3.y);
    }
    for (; p < pend; ++p) {
        long long v0 = __builtin_nontemporal_load(&ep[p]);
        ushort2 u0 = *(const ushort2*)&support[(size_t)(unsigned int)(v0 & 0xffffffff) * 128 + lane * 2];
        float f0 = __int_as_float((int)(v0 >> 32));
        ax += f0 * b2f(u0.x);
        ay += f0 * b2f(u0.y);
    }
}

// ---------------- K2/K3: fused spmm_k + gemm_{k+1} ----------------
// phase 1: each wave aggregates 16 nodes (relu+bias) -> LDS tile + featb slice
// phase 2: 64x128 MFMA tile from LDS with pW -> support_out
__global__ __launch_bounds__(256, 3)
void spmm_gemm_kernel(const int* __restrict__ row_ptr, const int2* __restrict__ epack,
                      const __hip_bfloat16* __restrict__ support_in,
                      const float* __restrict__ bias,
                      __hip_bfloat16* __restrict__ featb_slice,   // ld 256
                      const __hip_bfloat16* __restrict__ pW,
                      __hip_bfloat16* __restrict__ support_out, int M) {
    __shared__ unsigned short As[64][136];
    const int tid = threadIdx.x;
    const int wave = tid >> 6;
    const int lane = tid & 63;
    const int ln15 = lane & 15;
    const int quad = lane >> 4;
    const int m0 = blockIdx.x * 64;
    const long long* ep = (const long long*)epack;
    const float b0 = bias[lane * 2], b1v = bias[lane * 2 + 1];

    for (int i = 0; i < 16; ++i) {
        int r = wave * 16 + i;
        int node = m0 + r;
        float ax = 0.f, ay = 0.f;
        unsigned int packed = 0;
        if (node < M) {
            agg_node(row_ptr, ep, support_in, node, lane, ax, ay);
            ax = fmaxf(ax + b0, 0.f);
            ay = fmaxf(ay + b1v, 0.f);
            packed = (unsigned int)f2bb(ax) | ((unsigned int)f2bb(ay) << 16);
            __builtin_nontemporal_store(packed,
                (unsigned int*)&featb_slice[(size_t)node * 256 + lane * 2]);
        }
        *(unsigned int*)&As[r][lane * 2] = packed;
    }
    __syncthreads();

    f32x4 acc[4][2];
#pragma unroll
    for (int s = 0; s < 4; ++s)
#pragma unroll
        for (int h = 0; h < 2; ++h) acc[s][h] = (f32x4){0.f, 0.f, 0.f, 0.f};
#pragma unroll
    for (int kc = 0; kc < 4; ++kc) {
        short8 af[4];
#pragma unroll
        for (int s = 0; s < 4; ++s)
            af[s] = *(const short8*)&As[s * 16 + ln15][kc * 32 + quad * 8];
        short8 bf[2];
#pragma unroll
        for (int h = 0; h < 2; ++h)
            bf[h] = *(const short8*)&pW[((size_t)((wave * 2 + h) * 4 + kc) * 64 + lane) * 8];
#pragma unroll
        for (int s = 0; s < 4; ++s)
#pragma unroll
            for (int h = 0; h < 2; ++h)
                acc[s][h] = __builtin_amdgcn_mfma_f32_16x16x32_bf16(
                    af[s], bf[h], acc[s][h], 0, 0, 0);
    }

#pragma unroll
    for (int s = 0; s < 4; ++s)
#pragma unroll
        for (int h = 0; h < 2; ++h) {
            int col = (wave * 2 + h) * 16 + ln15;
#pragma unroll
            for (int r = 0; r < 4; ++r) {
                int row = m0 + s * 16 + quad * 4 + r;
                if (row < M)
                    support_out[(size_t)row * 128 + col] = __float2bfloat16(acc[s][h][r]);
            }
        }
}

// ---------------- K4: fused spmm3 + fc1 + fc2 + fc3 (g3 never leaves LDS) ----------------
__global__ __launch_bounds__(256, 3)
void spmm_fc_kernel(const int* __restrict__ row_ptr, const int2* __restrict__ epack,
                    const __hip_bfloat16* __restrict__ support_in,
                    const float* __restrict__ bias3,
                    const __hip_bfloat16* __restrict__ featb,   // ld 256 (g1|g2)
                    const __hip_bfloat16* __restrict__ pfcW1,
                    const float* __restrict__ fcb1,
                    const __hip_bfloat16* __restrict__ pfcW2,
                    const float* __restrict__ fcb2,
                    const float* __restrict__ fcW3, const float* __restrict__ fcb3,
                    float* __restrict__ out, int M) {
    __shared__ unsigned short As[64][136];
    __shared__ unsigned short Bs[64][136];
    __shared__ float w3s[128];
    __shared__ float b3s[2];
    const int tid = threadIdx.x;
    const int wave = tid >> 6;
    const int lane = tid & 63;
    const int ln15 = lane & 15;
    const int quad = lane >> 4;
    const int m0 = blockIdx.x * 64;
    const long long* ep = (const long long*)epack;
    if (tid < 128) w3s[tid] = fcW3[tid];
    if (tid < 2) b3s[tid] = fcb3[tid];
    const float b0 = bias3[lane * 2], b1v = bias3[lane * 2 + 1];

    // phase 1: g3 tile -> Bs only
    for (int i = 0; i < 16; ++i) {
        int r = wave * 16 + i;
        int node = m0 + r;
        float ax = 0.f, ay = 0.f;
        unsigned int packed = 0;
        if (node < M) {
            agg_node(row_ptr, ep, support_in, node, lane, ax, ay);
            ax = fmaxf(ax + b0, 0.f);
            ay = fmaxf(ay + b1v, 0.f);
            packed = (unsigned int)f2bb(ax) | ((unsigned int)f2bb(ay) << 16);
        }
        *(unsigned int*)&Bs[r][lane * 2] = packed;
    }
    __syncthreads();

    // fc1: K=384; kb=0,1 staged from featb, kb=2 from Bs
    f32x4 acc[4][2];
#pragma unroll
    for (int s = 0; s < 4; ++s)
#pragma unroll
        for (int h = 0; h < 2; ++h) acc[s][h] = (f32x4){0.f, 0.f, 0.f, 0.f};
    for (int kb = 0; kb < 2; ++kb) {
#pragma unroll
        for (int i = 0; i < 4; ++i) {
            int idx = tid + i * 256;
            int r = idx >> 4;
            int c8 = (idx & 15) * 8;
            uint4 v = {0, 0, 0, 0};
            if (m0 + r < M)
                v = *(const uint4*)&featb[(size_t)(m0 + r) * 256 + kb * 128 + c8];
            *(uint4*)&As[r][c8] = v;
        }
        __syncthreads();
#pragma unroll
        for (int kc = 0; kc < 4; ++kc) {
            short8 af[4];
#pragma unroll
            for (int s = 0; s < 4; ++s)
                af[s] = *(const short8*)&As[s * 16 + ln15][kc * 32 + quad * 8];
            short8 bf[2];
#pragma unroll
            for (int h = 0; h < 2; ++h) {
                int kcg = kb * 4 + kc;
                bf[h] = *(const short8*)&pfcW1[((size_t)((wave * 2 + h) * 12 + kcg) * 64 + lane) * 8];
            }
#pragma unroll
            for (int s = 0; s < 4; ++s)
#pragma unroll
                for (int h = 0; h < 2; ++h)
                    acc[s][h] = __builtin_amdgcn_mfma_f32_16x16x32_bf16(
                        af[s], bf[h], acc[s][h], 0, 0, 0);
        }
        __syncthreads();
    }
    // kb=2 from Bs
#pragma unroll
    for (int kc = 0; kc < 4; ++kc) {
        short8 af[4];
#pragma unroll
        for (int s = 0; s < 4; ++s)
            af[s] = *(const short8*)&Bs[s * 16 + ln15][kc * 32 + quad * 8];
        short8 bf[2];
#pragma unroll
        for (int h = 0; h < 2; ++h) {
            int kcg = 8 + kc;
            bf[h] = *(const short8*)&pfcW1[((size_t)((wave * 2 + h) * 12 + kcg) * 64 + lane) * 8];
        }
#pragma unroll
        for (int s = 0; s < 4; ++s)
#pragma unroll
            for (int h = 0; h < 2; ++h)
                acc[s][h] = __builtin_amdgcn_mfma_f32_16x16x32_bf16(
                    af[s], bf[h], acc[s][h], 0, 0, 0);
    }
    __syncthreads();
    // h1 tile (relu+bias) -> As
#pragma unroll
    for (int s = 0; s < 4; ++s)
#pragma unroll
        for (int h = 0; h < 2; ++h) {
            int col = (wave * 2 + h) * 16 + ln15;
            float bv = fcb1[col];
#pragma unroll
            for (int r = 0; r < 4; ++r) {
                int row = s * 16 + quad * 4 + r;
                As[row][col] = f2bb(fmaxf(acc[s][h][r] + bv, 0.f));
            }
        }
    __syncthreads();

    // fc2: K=128, N=64
    f32x4 acc2[4];
#pragma unroll
    for (int s = 0; s < 4; ++s) acc2[s] = (f32x4){0.f, 0.f, 0.f, 0.f};
#pragma unroll
    for (int kc = 0; kc < 4; ++kc) {
        short8 af[4];
#pragma unroll
        for (int s = 0; s < 4; ++s)
            af[s] = *(const short8*)&As[s * 16 + ln15][kc * 32 + quad * 8];
        short8 bfw = *(const short8*)&pfcW2[((size_t)(wave * 4 + kc) * 64 + lane) * 8];
#pragma unroll
        for (int s = 0; s < 4; ++s)
            acc2[s] = __builtin_amdgcn_mfma_f32_16x16x32_bf16(af[s], bfw, acc2[s], 0, 0, 0);
    }
    __syncthreads();
    {
        int col2 = wave * 16 + ln15;
        float bv = fcb2[col2];
#pragma unroll
        for (int s = 0; s < 4; ++s)
#pragma unroll
            for (int r = 0; r < 4; ++r) {
                int row = s * 16 + quad * 4 + r;
                As[row][col2] = f2bb(fmaxf(acc2[s][r] + bv, 0.f));
            }
    }
    __syncthreads();

    // fc3: 64 -> 2
    if (tid < 128) {
        int row = tid >> 1, cls = tid & 1;
        int grow = m0 + row;
        if (grow < M) {
            float a = b3s[cls];
#pragma unroll
            for (int k = 0; k < 64; ++k)
                a += b2f(As[row][k]) * w3s[k * 2 + cls];
            out[(size_t)grow * 2 + cls] = a;
        }
    }
}

extern "C" void kernel_launch(void* const* d_in, const int* in_sizes, int n_in,
                              void* d_out, int out_size, void* d_ws, size_t ws_size,
                              hipStream_t stream) {
    const int*   adj_row  = (const int*)d_in[0];
    const int*   adj_col  = (const int*)d_in[1];
    const float* adj_vals = (const float*)d_in[2];
    const float* x        = (const float*)d_in[3];
    const float* W1   = (const float*)d_in[5];
    const float* b1   = (const float*)d_in[6];
    const float* W2   = (const float*)d_in[7];
    const float* b2   = (const float*)d_in[8];
    const float* W3   = (const float*)d_in[9];
    const float* b3   = (const float*)d_in[10];
    const float* fcW1 = (const float*)d_in[11];
    const float* fcb1 = (const float*)d_in[12];
    const float* fcW2 = (const float*)d_in[13];
    const float* fcb2 = (const float*)d_in[14];
    const float* fcW3 = (const float*)d_in[15];
    const float* fcb3 = (const float*)d_in[16];
    float* out = (float*)d_out;

    const int N = N_NODES, E = N_EDGES;
    const int Mpad = 50048;

    char* p = (char*)d_ws;
    auto alloc = [&](size_t bytes) {
        char* q = p;
        p += (bytes + 255) & ~(size_t)255;
        return q;
    };
    __hip_bfloat16* featb    = (__hip_bfloat16*)alloc((size_t)Mpad * 256 * 2); // g1|g2
    __hip_bfloat16* supportA = (__hip_bfloat16*)alloc((size_t)Mpad * 128 * 2);
    __hip_bfloat16* supportB = (__hip_bfloat16*)alloc((size_t)Mpad * 128 * 2);
    __hip_bfloat16* pW1   = (__hip_bfloat16*)alloc(16384 * 2);
    __hip_bfloat16* pW2   = (__hip_bfloat16*)alloc(16384 * 2);
    __hip_bfloat16* pW3   = (__hip_bfloat16*)alloc(16384 * 2);
    __hip_bfloat16* pfcW1 = (__hip_bfloat16*)alloc(49152 * 2);
    __hip_bfloat16* pfcW2 = (__hip_bfloat16*)alloc(8192 * 2);
    int*   row_ptr   = (int*)alloc((size_t)(N + 1) * 4);
    int*   bbase     = (int*)alloc((size_t)(NBK + 1) * 4);
    int*   bcursor   = (int*)alloc((size_t)NBK * 4);
    int2*  epack     = (int2*)alloc((size_t)E * 8);
    int2*  tmp       = (int2*)alloc((size_t)NBK * BCAP * 8);  // dead after binB

    // ---- prep + CSR build ----
    prep_kernel<<<54, 256, 0, stream>>>(W1, W2, W3, fcW1, fcW2,
                                        pW1, pW2, pW3, pfcW1, pfcW2, bcursor);
    binA_kernel<<<cdiv(E, 4096), 256, 0, stream>>>(adj_row, adj_col, adj_vals,
                                                   bcursor, tmp, E);
    bscan_kernel<<<1, 512, 0, stream>>>(bcursor, bbase);
    binB_kernel<<<NBK, 256, 0, stream>>>(tmp, bcursor, bbase, row_ptr, epack, N);

    const int grid = cdiv(N, 64);

    // K1: support1 = x @ W1
    gemm1_kernel<<<grid, 256, 0, stream>>>(x, pW1, supportA, N);
    // K2: g1 = relu(A@support1 + b1) -> featb[:,0:128]; support2 = g1 @ W2
    spmm_gemm_kernel<<<grid, 256, 0, stream>>>(row_ptr, epack, supportA, b1,
                                               featb + 0, pW2, supportB, N);
    // K3: g2 -> featb[:,128:256]; support3 = g2 @ W3
    spmm_gemm_kernel<<<grid, 256, 0, stream>>>(row_ptr, epack, supportB, b2,
                                               featb + 128, pW3, supportA, N);
    // K4: g3 (LDS only) + fc1 + fc2 + fc3 -> out
    spmm_fc_kernel<<<grid, 256, 0, stream>>>(row_ptr, epack, supportA, b3,
                                             featb, pfcW1, fcb1, pfcW2, fcb2,
                                             fcW3, fcb3, out, N);
}

// Round 11
// 329.306 us; speedup vs baseline: 1.2479x; 1.2479x over previous
//
#include <hip/hip_runtime.h>
#include <hip/hip_bf16.h>

#define N_NODES 50000
#define N_EDGES 800000
#define NBK 391          // ceil(50000/128) row buckets of 128 rows
#define BCAP 2560        // slab capacity per bucket (mean 2048 + 11 sigma)

static inline int cdiv(int a, int b) { return (a + b - 1) / b; }

typedef __attribute__((ext_vector_type(8))) short short8;
typedef __attribute__((ext_vector_type(4))) float f32x4;

__device__ __forceinline__ float b2f(unsigned short u) {
    union { unsigned int i; float f; } c;
    c.i = ((unsigned int)u) << 16;
    return c.f;
}
__device__ __forceinline__ unsigned short f2bb(float f) {
    __hip_bfloat16 h = __float2bfloat16(f);
    return *(unsigned short*)&h;
}

__device__ __forceinline__ void pack_one(const float* __restrict__ W,
                                         __hip_bfloat16* __restrict__ out,
                                         int K, int N, int t) {
    int lane = t & 63;
    int kc = (t >> 6) % (K / 32);
    int nt = (t >> 6) / (K / 32);
    int kbase = kc * 32 + (lane >> 4) * 8;
    int col = nt * 16 + (lane & 15);
    __hip_bfloat16* dst = out + (size_t)t * 8;
#pragma unroll
    for (int j = 0; j < 8; ++j)
        dst[j] = __float2bfloat16(W[(size_t)(kbase + j) * N + col]);
}

// ---------------- stage1: binA (blocks 0..195) + gemm1 (196..977) + packs (978..1021) ----------------
// All three are independent: binA touches adj/tmp/bcursor, gemm1 reads x+raw W1 -> support,
// packs read W2/W3/fcW1/fcW2 -> pW*. bcursor holds pure counts (slab base added here).
__global__ __launch_bounds__(256)
void stage1_kernel(const int* __restrict__ row, const int* __restrict__ col,
                   const float* __restrict__ vals, int* __restrict__ bcursor,
                   int2* __restrict__ tmp, int E,
                   const float* __restrict__ x, __hip_bfloat16* __restrict__ support,
                   int M,
                   const float* __restrict__ W1, const float* __restrict__ W2,
                   const float* __restrict__ W3, const float* __restrict__ fcW1,
                   const float* __restrict__ fcW2,
                   __hip_bfloat16* __restrict__ pW2, __hip_bfloat16* __restrict__ pW3,
                   __hip_bfloat16* __restrict__ pfcW1, __hip_bfloat16* __restrict__ pfcW2) {
    __shared__ unsigned short As[64][136];
    __shared__ int hist[NBK];
    __shared__ int base[NBK];
    const int b = blockIdx.x;
    const int tid = threadIdx.x;

    if (b < 196) {
        // ---- binA: bin 4096 edges into bucket slabs ----
        const int CH = 4096;
        int e0 = b * CH;
        for (int i = tid; i < NBK; i += 256) hist[i] = 0;
        __syncthreads();
        for (int i = tid; i < CH; i += 256) {
            int e = e0 + i;
            if (e < E) atomicAdd(&hist[row[e] >> 7], 1);
        }
        __syncthreads();
        for (int i = tid; i < NBK; i += 256) {
            int c = hist[i];
            base[i] = (c > 0) ? (i * BCAP + atomicAdd(&bcursor[i], c)) : 0;
            hist[i] = 0;
        }
        __syncthreads();
        for (int i = tid; i < CH; i += 256) {
            int e = e0 + i;
            if (e < E) {
                int r = row[e];
                int bk = r >> 7;
                int rk = atomicAdd(&hist[bk], 1);
                tmp[base[bk] + rk] = make_int2(((r & 127) << 16) | col[e],
                                               __float_as_int(vals[e]));
            }
        }
        return;
    }

    if (b < 978) {
        // ---- gemm1: support = bf16(x) @ bf16(W1), self-packed B frags from raw W1 ----
        const int wave = tid >> 6;
        const int lane = tid & 63;
        const int ln15 = lane & 15;
        const int quad = lane >> 4;
        const int m0 = (b - 196) * 64;

        short8 bfr[4][2];
#pragma unroll
        for (int kc = 0; kc < 4; ++kc)
#pragma unroll
            for (int h = 0; h < 2; ++h)
#pragma unroll
                for (int j = 0; j < 8; ++j)
                    bfr[kc][h][j] = (short)f2bb(
                        W1[(size_t)(kc * 32 + quad * 8 + j) * 128 + (wave * 2 + h) * 16 + ln15]);

#pragma unroll
        for (int i = 0; i < 4; ++i) {
            int idx = tid + i * 256;
            int r = idx >> 4;
            int c8 = (idx & 15) * 8;
            uint4 pk = {0, 0, 0, 0};
            if (m0 + r < M) {
                const float* src = &x[(size_t)(m0 + r) * 128 + c8];
                float4 a = *(const float4*)src;
                float4 bq = *(const float4*)(src + 4);
                pk.x = f2bb(a.x) | ((unsigned int)f2bb(a.y) << 16);
                pk.y = f2bb(a.z) | ((unsigned int)f2bb(a.w) << 16);
                pk.z = f2bb(bq.x) | ((unsigned int)f2bb(bq.y) << 16);
                pk.w = f2bb(bq.z) | ((unsigned int)f2bb(bq.w) << 16);
            }
            *(uint4*)&As[r][c8] = pk;
        }
        __syncthreads();

        f32x4 acc[4][2];
#pragma unroll
        for (int s = 0; s < 4; ++s)
#pragma unroll
            for (int h = 0; h < 2; ++h) acc[s][h] = (f32x4){0.f, 0.f, 0.f, 0.f};
#pragma unroll
        for (int kc = 0; kc < 4; ++kc) {
            short8 af[4];
#pragma unroll
            for (int s = 0; s < 4; ++s)
                af[s] = *(const short8*)&As[s * 16 + ln15][kc * 32 + quad * 8];
#pragma unroll
            for (int s = 0; s < 4; ++s)
#pragma unroll
                for (int h = 0; h < 2; ++h)
                    acc[s][h] = __builtin_amdgcn_mfma_f32_16x16x32_bf16(
                        af[s], bfr[kc][h], acc[s][h], 0, 0, 0);
        }
#pragma unroll
        for (int s = 0; s < 4; ++s)
#pragma unroll
            for (int h = 0; h < 2; ++h) {
                int cl = (wave * 2 + h) * 16 + ln15;
#pragma unroll
                for (int r = 0; r < 4; ++r) {
                    int rw = m0 + s * 16 + quad * 4 + r;
                    if (rw < M)
                        support[(size_t)rw * 128 + cl] = __float2bfloat16(acc[s][h][r]);
                }
            }
        return;
    }

    // ---- weight packing for W2/W3/fcW1/fcW2 ----
    int pb = b - 978;
    if (pb < 8)       pack_one(W2,  pW2,  128, 128, pb * 256 + tid);
    else if (pb < 16) pack_one(W3,  pW3,  128, 128, (pb - 8) * 256 + tid);
    else if (pb < 40) pack_one(fcW1, pfcW1, 384, 128, (pb - 16) * 256 + tid);
    else              pack_one(fcW2, pfcW2, 128, 64, (pb - 40) * 256 + tid);
}

// ---------------- CSR: bucket scan + per-bucket counting sort ----------------

__global__ __launch_bounds__(512)
void bscan_kernel(const int* __restrict__ bcursor, int* __restrict__ bbase) {
    __shared__ int s[512];
    int t = threadIdx.x;
    int v = (t < NBK) ? bcursor[t] : 0;
    s[t] = v;
    __syncthreads();
    for (int off = 1; off < 512; off <<= 1) {
        int u = (t >= off) ? s[t - off] : 0;
        __syncthreads();
        s[t] += u;
        __syncthreads();
    }
    if (t < NBK) bbase[t] = s[t] - v;
    if (t == NBK - 1) bbase[NBK] = s[t];
}

__global__ __launch_bounds__(256)
void binB_kernel(const int2* __restrict__ tmp, const int* __restrict__ bcursor,
                 const int* __restrict__ bbase, int* __restrict__ row_ptr,
                 int2* __restrict__ epack, int N) {
    int b = blockIdx.x;
    int r0 = b << 7;
    int nr = N - r0; if (nr > 128) nr = 128;
    __shared__ int cnt[128];
    __shared__ int cur[128];
    int t = threadIdx.x;
    if (t < 128) cnt[t] = 0;
    __syncthreads();
    int slab = b * BCAP;
    int send = slab + bcursor[b];
    int obase = bbase[b];
    for (int i = slab + t; i < send; i += 256)
        atomicAdd(&cnt[tmp[i].x >> 16], 1);
    __syncthreads();
    if (t < 128) cur[t] = cnt[t];
    __syncthreads();
    for (int off = 1; off < 128; off <<= 1) {
        int u = (t >= off && t < 128) ? cur[t - off] : 0;
        __syncthreads();
        if (t < 128) cur[t] += u;
        __syncthreads();
    }
    if (t < 128) {
        int ex = cur[t] - cnt[t];
        int pos = obase + ex;
        cur[t] = pos;
        if (t < nr) row_ptr[r0 + t] = pos;
    }
    if (b == NBK - 1 && t == 128) row_ptr[N] = bbase[NBK];
    __syncthreads();
    for (int i = slab + t; i < send; i += 256) {
        int2 v = tmp[i];
        int rl = v.x >> 16;
        int c = v.x & 0xffff;
        int pos = atomicAdd(&cur[rl], 1);
        epack[pos] = make_int2(c, v.y);
    }
}

// ---------------- bf16 MFMA GEMM (layer GEMMs 2,3) ----------------
__global__ __launch_bounds__(256, 3)
void mfma_gemm(const __hip_bfloat16* __restrict__ A, int lda,
               const __hip_bfloat16* __restrict__ pW,
               __hip_bfloat16* __restrict__ C, int M) {
    __shared__ unsigned short As[64][136];
    const int tid = threadIdx.x;
    const int wave = tid >> 6;
    const int lane = tid & 63;
    const int ln15 = lane & 15;
    const int quad = lane >> 4;
    const int m0 = blockIdx.x * 64;
    const int ntw = wave * 2;

    f32x4 acc[4][2];
#pragma unroll
    for (int s = 0; s < 4; ++s)
#pragma unroll
        for (int h = 0; h < 2; ++h) acc[s][h] = (f32x4){0.f, 0.f, 0.f, 0.f};

#pragma unroll
    for (int i = 0; i < 4; ++i) {
        int idx = tid + i * 256;
        int r = idx >> 4;
        int c8 = (idx & 15) * 8;
        uint4 v = *(const uint4*)&A[(size_t)(m0 + r) * lda + c8];
        *(uint4*)&As[r][c8] = v;
    }
    __syncthreads();
#pragma unroll
    for (int kc = 0; kc < 4; ++kc) {
        short8 af[4];
#pragma unroll
        for (int s = 0; s < 4; ++s)
            af[s] = *(const short8*)&As[s * 16 + ln15][kc * 32 + quad * 8];
        short8 bf[2];
#pragma unroll
        for (int h = 0; h < 2; ++h)
            bf[h] = *(const short8*)&pW[((size_t)((ntw + h) * 4 + kc) * 64 + lane) * 8];
#pragma unroll
        for (int s = 0; s < 4; ++s)
#pragma unroll
            for (int h = 0; h < 2; ++h)
                acc[s][h] = __builtin_amdgcn_mfma_f32_16x16x32_bf16(
                    af[s], bf[h], acc[s][h], 0, 0, 0);
    }

#pragma unroll
    for (int s = 0; s < 4; ++s)
#pragma unroll
        for (int h = 0; h < 2; ++h) {
            int cl = (ntw + h) * 16 + ln15;
#pragma unroll
            for (int r = 0; r < 4; ++r) {
                int rw = m0 + s * 16 + quad * 4 + r;
                if (rw < M)
                    C[(size_t)rw * 128 + cl] = __float2bfloat16(acc[s][h][r]);
            }
        }
}

// ---------------- SpMM: 1 node/wave, grid 12500 (TLP is the resource) ----------------
__global__ __launch_bounds__(256)
void spmm_kernel(const int* __restrict__ row_ptr, const int2* __restrict__ epack,
                 const __hip_bfloat16* __restrict__ support,
                 const float* __restrict__ bias, __hip_bfloat16* __restrict__ out,
                 int ldo, int n) {
    int wv = threadIdx.x >> 6;
    int l = threadIdx.x & 63;
    int node = blockIdx.x * 4 + wv;
    if (node >= n) return;
    const long long* ep = (const long long*)epack;
    int start = row_ptr[node], end = row_ptr[node + 1];
    float ax = 0.f, ay = 0.f;
    int p = start;
    for (; p + 4 <= end; p += 4) {
        long long v0 = __builtin_nontemporal_load(&ep[p]);
        long long v1 = __builtin_nontemporal_load(&ep[p + 1]);
        long long v2 = __builtin_nontemporal_load(&ep[p + 2]);
        long long v3 = __builtin_nontemporal_load(&ep[p + 3]);
        ushort2 u0 = *(const ushort2*)&support[(size_t)(unsigned int)(v0 & 0xffffffff) * 128 + l * 2];
        ushort2 u1 = *(const ushort2*)&support[(size_t)(unsigned int)(v1 & 0xffffffff) * 128 + l * 2];
        ushort2 u2 = *(const ushort2*)&support[(size_t)(unsigned int)(v2 & 0xffffffff) * 128 + l * 2];
        ushort2 u3 = *(const ushort2*)&support[(size_t)(unsigned int)(v3 & 0xffffffff) * 128 + l * 2];
        float f0 = __int_as_float((int)(v0 >> 32));
        float f1 = __int_as_float((int)(v1 >> 32));
        float f2 = __int_as_float((int)(v2 >> 32));
        float f3 = __int_as_float((int)(v3 >> 32));
        ax += f0 * b2f(u0.x) + f1 * b2f(u1.x) + f2 * b2f(u2.x) + f3 * b2f(u3.x);
        ay += f0 * b2f(u0.y) + f1 * b2f(u1.y) + f2 * b2f(u2.y) + f3 * b2f(u3.y);
    }
    for (; p < end; ++p) {
        long long v0 = __builtin_nontemporal_load(&ep[p]);
        ushort2 u0 = *(const ushort2*)&support[(size_t)(unsigned int)(v0 & 0xffffffff) * 128 + l * 2];
        float f0 = __int_as_float((int)(v0 >> 32));
        ax += f0 * b2f(u0.x);
        ay += f0 * b2f(u0.y);
    }
    unsigned int packed = (unsigned int)f2bb(fmaxf(ax + bias[l * 2 + 0], 0.f))
                        | ((unsigned int)f2bb(fmaxf(ay + bias[l * 2 + 1], 0.f)) << 16);
    __builtin_nontemporal_store(packed, (unsigned int*)&out[(size_t)node * ldo + l * 2]);
}

// ---------------- fused FC head (round-9 form) ----------------
__global__ __launch_bounds__(256, 3)
void fc123_kernel(const __hip_bfloat16* __restrict__ featb,
                  const __hip_bfloat16* __restrict__ pfcW1,
                  const float* __restrict__ fcb1,
                  const __hip_bfloat16* __restrict__ pfcW2,
                  const float* __restrict__ fcb2,
                  const float* __restrict__ fcW3, const float* __restrict__ fcb3,
                  float* __restrict__ out, int M) {
    __shared__ unsigned short As[64][136];
    __shared__ float w3s[128];
    __shared__ float b3s[2];
    const int tid = threadIdx.x;
    const int wave = tid >> 6;
    const int lane = tid & 63;
    const int ln15 = lane & 15;
    const int quad = lane >> 4;
    const int m0 = blockIdx.x * 64;
    if (tid < 128) w3s[tid] = fcW3[tid];
    if (tid < 2) b3s[tid] = fcb3[tid];

    f32x4 acc[4][2];
#pragma unroll
    for (int s = 0; s < 4; ++s)
#pragma unroll
        for (int h = 0; h < 2; ++h) acc[s][h] = (f32x4){0.f, 0.f, 0.f, 0.f};
    for (int kb = 0; kb < 3; ++kb) {
#pragma unroll
        for (int i = 0; i < 4; ++i) {
            int idx = tid + i * 256;
            int r = idx >> 4;
            int c8 = (idx & 15) * 8;
            uint4 v = *(const uint4*)&featb[(size_t)(m0 + r) * 384 + kb * 128 + c8];
            *(uint4*)&As[r][c8] = v;
        }
        __syncthreads();
#pragma unroll
        for (int kc = 0; kc < 4; ++kc) {
            short8 af[4];
#pragma unroll
            for (int s = 0; s < 4; ++s)
                af[s] = *(const short8*)&As[s * 16 + ln15][kc * 32 + quad * 8];
            short8 bf[2];
#pragma unroll
            for (int h = 0; h < 2; ++h) {
                int kcg = kb * 4 + kc;
                bf[h] = *(const short8*)&pfcW1[((size_t)((wave * 2 + h) * 12 + kcg) * 64 + lane) * 8];
            }
#pragma unroll
            for (int s = 0; s < 4; ++s)
#pragma unroll
                for (int h = 0; h < 2; ++h)
                    acc[s][h] = __builtin_amdgcn_mfma_f32_16x16x32_bf16(
                        af[s], bf[h], acc[s][h], 0, 0, 0);
        }
        __syncthreads();
    }
#pragma unroll
    for (int s = 0; s < 4; ++s)
#pragma unroll
        for (int h = 0; h < 2; ++h) {
            int col = (wave * 2 + h) * 16 + ln15;
            float bv = fcb1[col];
#pragma unroll
            for (int r = 0; r < 4; ++r) {
                int row = s * 16 + quad * 4 + r;
                As[row][col] = f2bb(fmaxf(acc[s][h][r] + bv, 0.f));
            }
        }
    __syncthreads();

    f32x4 acc2[4];
#pragma unroll
    for (int s = 0; s < 4; ++s) acc2[s] = (f32x4){0.f, 0.f, 0.f, 0.f};
#pragma unroll
    for (int kc = 0; kc < 4; ++kc) {
        short8 af[4];
#pragma unroll
        for (int s = 0; s < 4; ++s)
            af[s] = *(const short8*)&As[s * 16 + ln15][kc * 32 + quad * 8];
        short8 bfw = *(const short8*)&pfcW2[((size_t)(wave * 4 + kc) * 64 + lane) * 8];
#pragma unroll
        for (int s = 0; s < 4; ++s)
            acc2[s] = __builtin_amdgcn_mfma_f32_16x16x32_bf16(af[s], bfw, acc2[s], 0, 0, 0);
    }
    __syncthreads();
    {
        int col2 = wave * 16 + ln15;
        float bv = fcb2[col2];
#pragma unroll
        for (int s = 0; s < 4; ++s)
#pragma unroll
            for (int r = 0; r < 4; ++r) {
                int row = s * 16 + quad * 4 + r;
                As[row][col2] = f2bb(fmaxf(acc2[s][r] + bv, 0.f));
            }
    }
    __syncthreads();

    if (tid < 128) {
        int row = tid >> 1, cls = tid & 1;
        int grow = m0 + row;
        if (grow < M) {
            float a = b3s[cls];
#pragma unroll
            for (int k = 0; k < 64; ++k)
                a += b2f(As[row][k]) * w3s[k * 2 + cls];
            out[(size_t)grow * 2 + cls] = a;
        }
    }
}

extern "C" void kernel_launch(void* const* d_in, const int* in_sizes, int n_in,
                              void* d_out, int out_size, void* d_ws, size_t ws_size,
                              hipStream_t stream) {
    const int*   adj_row  = (const int*)d_in[0];
    const int*   adj_col  = (const int*)d_in[1];
    const float* adj_vals = (const float*)d_in[2];
    const float* x        = (const float*)d_in[3];
    const float* W1   = (const float*)d_in[5];
    const float* b1   = (const float*)d_in[6];
    const float* W2   = (const float*)d_in[7];
    const float* b2   = (const float*)d_in[8];
    const float* W3   = (const float*)d_in[9];
    const float* b3   = (const float*)d_in[10];
    const float* fcW1 = (const float*)d_in[11];
    const float* fcb1 = (const float*)d_in[12];
    const float* fcW2 = (const float*)d_in[13];
    const float* fcb2 = (const float*)d_in[14];
    const float* fcW3 = (const float*)d_in[15];
    const float* fcb3 = (const float*)d_in[16];
    float* out = (float*)d_out;

    const int N = N_NODES, E = N_EDGES;
    const int Mpad = 50048;

    char* p = (char*)d_ws;
    auto alloc = [&](size_t bytes) {
        char* q = p;
        p += (bytes + 255) & ~(size_t)255;
        return q;
    };
    __hip_bfloat16* featb    = (__hip_bfloat16*)alloc((size_t)Mpad * 384 * 2); // g1|g2|g3
    __hip_bfloat16* supportb = (__hip_bfloat16*)alloc((size_t)Mpad * 128 * 2);
    __hip_bfloat16* pW2   = (__hip_bfloat16*)alloc(16384 * 2);
    __hip_bfloat16* pW3   = (__hip_bfloat16*)alloc(16384 * 2);
    __hip_bfloat16* pfcW1 = (__hip_bfloat16*)alloc(49152 * 2);
    __hip_bfloat16* pfcW2 = (__hip_bfloat16*)alloc(8192 * 2);
    int*   row_ptr   = (int*)alloc((size_t)(N + 1) * 4);
    int*   bbase     = (int*)alloc((size_t)(NBK + 1) * 4);
    int*   bcursor   = (int*)alloc((size_t)NBK * 4);
    int2*  epack     = (int2*)alloc((size_t)E * 8);
    int2*  tmp       = (int2*)alloc((size_t)NBK * BCAP * 8);

    // ---- stage1: binA + gemm1 + weight packs in one launch ----
    hipMemsetAsync(bcursor, 0, (size_t)NBK * 4, stream);
    stage1_kernel<<<1022, 256, 0, stream>>>(adj_row, adj_col, adj_vals, bcursor, tmp, E,
                                            x, supportb, N,
                                            W1, W2, W3, fcW1, fcW2,
                                            pW2, pW3, pfcW1, pfcW2);
    bscan_kernel<<<1, 512, 0, stream>>>(bcursor, bbase);
    binB_kernel<<<NBK, 256, 0, stream>>>(tmp, bcursor, bbase, row_ptr, epack, N);

    const int gemmGrid = cdiv(N, 64);
    const int spmmGrid = cdiv(N, 4);

    // ---- GCN layer 1 aggregate ----
    spmm_kernel<<<spmmGrid, 256, 0, stream>>>(row_ptr, epack, supportb, b1,
                                              featb + 0, 384, N);
    // ---- GCN layer 2 ----
    mfma_gemm<<<gemmGrid, 256, 0, stream>>>(featb + 0, 384, pW2, supportb, N);
    spmm_kernel<<<spmmGrid, 256, 0, stream>>>(row_ptr, epack, supportb, b2,
                                              featb + 128, 384, N);
    // ---- GCN layer 3 ----
    mfma_gemm<<<gemmGrid, 256, 0, stream>>>(featb + 128, 384, pW3, supportb, N);
    spmm_kernel<<<spmmGrid, 256, 0, stream>>>(row_ptr, epack, supportb, b3,
                                              featb + 256, 384, N);

    // ---- fused FC head ----
    fc123_kernel<<<gemmGrid, 256, 0, stream>>>(featb, pfcW1, fcb1, pfcW2, fcb2,
                                               fcW3, fcb3, out, N);
}

// Round 12
// 296.440 us; speedup vs baseline: 1.3862x; 1.1109x over previous
//
#include <hip/hip_runtime.h>
#include <hip/hip_bf16.h>

#define N_NODES 50000
#define N_EDGES 800000
#define NBK 391          // ceil(50000/128) row buckets of 128 rows
#define BCAP 2560        // slab capacity per bucket (mean 2048 + 11 sigma)

static inline int cdiv(int a, int b) { return (a + b - 1) / b; }

typedef __attribute__((ext_vector_type(8))) short short8;
typedef __attribute__((ext_vector_type(4))) float f32x4;

__device__ __forceinline__ float b2f(unsigned short u) {
    union { unsigned int i; float f; } c;
    c.i = ((unsigned int)u) << 16;
    return c.f;
}
__device__ __forceinline__ unsigned short f2bb(float f) {
    __hip_bfloat16 h = __float2bfloat16(f);
    return *(unsigned short*)&h;
}

__device__ __forceinline__ void pack_one(const float* __restrict__ W,
                                         __hip_bfloat16* __restrict__ out,
                                         int K, int N, int t) {
    int lane = t & 63;
    int kc = (t >> 6) % (K / 32);
    int nt = (t >> 6) / (K / 32);
    int kbase = kc * 32 + (lane >> 4) * 8;
    int col = nt * 16 + (lane & 15);
    __hip_bfloat16* dst = out + (size_t)t * 8;
#pragma unroll
    for (int j = 0; j < 8; ++j)
        dst[j] = __float2bfloat16(W[(size_t)(kbase + j) * N + col]);
}

// ---------------- stage1: binA (blocks 0..195) + gemm1 (196..977) + packs (978..1021) ----------------
__global__ __launch_bounds__(256)
void stage1_kernel(const int* __restrict__ row, const int* __restrict__ col,
                   const float* __restrict__ vals, int* __restrict__ bcursor,
                   int2* __restrict__ tmp, int E,
                   const float* __restrict__ x, __hip_bfloat16* __restrict__ support,
                   int M,
                   const float* __restrict__ W1, const float* __restrict__ W2,
                   const float* __restrict__ W3, const float* __restrict__ fcW1,
                   const float* __restrict__ fcW2,
                   __hip_bfloat16* __restrict__ pW2, __hip_bfloat16* __restrict__ pW3,
                   __hip_bfloat16* __restrict__ pfcW1, __hip_bfloat16* __restrict__ pfcW2) {
    __shared__ unsigned short As[64][136];
    __shared__ int hist[NBK];
    __shared__ int base[NBK];
    const int b = blockIdx.x;
    const int tid = threadIdx.x;

    if (b < 196) {
        const int CH = 4096;
        int e0 = b * CH;
        for (int i = tid; i < NBK; i += 256) hist[i] = 0;
        __syncthreads();
        for (int i = tid; i < CH; i += 256) {
            int e = e0 + i;
            if (e < E) atomicAdd(&hist[row[e] >> 7], 1);
        }
        __syncthreads();
        for (int i = tid; i < NBK; i += 256) {
            int c = hist[i];
            base[i] = (c > 0) ? (i * BCAP + atomicAdd(&bcursor[i], c)) : 0;
            hist[i] = 0;
        }
        __syncthreads();
        for (int i = tid; i < CH; i += 256) {
            int e = e0 + i;
            if (e < E) {
                int r = row[e];
                int bk = r >> 7;
                int rk = atomicAdd(&hist[bk], 1);
                tmp[base[bk] + rk] = make_int2(((r & 127) << 16) | col[e],
                                               __float_as_int(vals[e]));
            }
        }
        return;
    }

    if (b < 978) {
        const int wave = tid >> 6;
        const int lane = tid & 63;
        const int ln15 = lane & 15;
        const int quad = lane >> 4;
        const int m0 = (b - 196) * 64;

        short8 bfr[4][2];
#pragma unroll
        for (int kc = 0; kc < 4; ++kc)
#pragma unroll
            for (int h = 0; h < 2; ++h)
#pragma unroll
                for (int j = 0; j < 8; ++j)
                    bfr[kc][h][j] = (short)f2bb(
                        W1[(size_t)(kc * 32 + quad * 8 + j) * 128 + (wave * 2 + h) * 16 + ln15]);

#pragma unroll
        for (int i = 0; i < 4; ++i) {
            int idx = tid + i * 256;
            int r = idx >> 4;
            int c8 = (idx & 15) * 8;
            uint4 pk = {0, 0, 0, 0};
            if (m0 + r < M) {
                const float* src = &x[(size_t)(m0 + r) * 128 + c8];
                float4 a = *(const float4*)src;
                float4 bq = *(const float4*)(src + 4);
                pk.x = f2bb(a.x) | ((unsigned int)f2bb(a.y) << 16);
                pk.y = f2bb(a.z) | ((unsigned int)f2bb(a.w) << 16);
                pk.z = f2bb(bq.x) | ((unsigned int)f2bb(bq.y) << 16);
                pk.w = f2bb(bq.z) | ((unsigned int)f2bb(bq.w) << 16);
            }
            *(uint4*)&As[r][c8] = pk;
        }
        __syncthreads();

        f32x4 acc[4][2];
#pragma unroll
        for (int s = 0; s < 4; ++s)
#pragma unroll
            for (int h = 0; h < 2; ++h) acc[s][h] = (f32x4){0.f, 0.f, 0.f, 0.f};
#pragma unroll
        for (int kc = 0; kc < 4; ++kc) {
            short8 af[4];
#pragma unroll
            for (int s = 0; s < 4; ++s)
                af[s] = *(const short8*)&As[s * 16 + ln15][kc * 32 + quad * 8];
#pragma unroll
            for (int s = 0; s < 4; ++s)
#pragma unroll
                for (int h = 0; h < 2; ++h)
                    acc[s][h] = __builtin_amdgcn_mfma_f32_16x16x32_bf16(
                        af[s], bfr[kc][h], acc[s][h], 0, 0, 0);
        }
#pragma unroll
        for (int s = 0; s < 4; ++s)
#pragma unroll
            for (int h = 0; h < 2; ++h) {
                int cl = (wave * 2 + h) * 16 + ln15;
#pragma unroll
                for (int r = 0; r < 4; ++r) {
                    int rw = m0 + s * 16 + quad * 4 + r;
                    if (rw < M)
                        support[(size_t)rw * 128 + cl] = __float2bfloat16(acc[s][h][r]);
                }
            }
        return;
    }

    int pb = b - 978;
    if (pb < 8)       pack_one(W2,  pW2,  128, 128, pb * 256 + tid);
    else if (pb < 16) pack_one(W3,  pW3,  128, 128, (pb - 8) * 256 + tid);
    else if (pb < 40) pack_one(fcW1, pfcW1, 384, 128, (pb - 16) * 256 + tid);
    else              pack_one(fcW2, pfcW2, 128, 64, (pb - 40) * 256 + tid);
}

// ---------------- CSR: bucket scan + per-bucket counting sort ----------------

__global__ __launch_bounds__(512)
void bscan_kernel(const int* __restrict__ bcursor, int* __restrict__ bbase) {
    __shared__ int s[512];
    int t = threadIdx.x;
    int v = (t < NBK) ? bcursor[t] : 0;
    s[t] = v;
    __syncthreads();
    for (int off = 1; off < 512; off <<= 1) {
        int u = (t >= off) ? s[t - off] : 0;
        __syncthreads();
        s[t] += u;
        __syncthreads();
    }
    if (t < NBK) bbase[t] = s[t] - v;
    if (t == NBK - 1) bbase[NBK] = s[t];
}

__global__ __launch_bounds__(256)
void binB_kernel(const int2* __restrict__ tmp, const int* __restrict__ bcursor,
                 const int* __restrict__ bbase, int* __restrict__ row_ptr,
                 int2* __restrict__ epack, int N) {
    int b = blockIdx.x;
    int r0 = b << 7;
    int nr = N - r0; if (nr > 128) nr = 128;
    __shared__ int cnt[128];
    __shared__ int cur[128];
    int t = threadIdx.x;
    if (t < 128) cnt[t] = 0;
    __syncthreads();
    int slab = b * BCAP;
    int send = slab + bcursor[b];
    int obase = bbase[b];
    for (int i = slab + t; i < send; i += 256)
        atomicAdd(&cnt[tmp[i].x >> 16], 1);
    __syncthreads();
    if (t < 128) cur[t] = cnt[t];
    __syncthreads();
    for (int off = 1; off < 128; off <<= 1) {
        int u = (t >= off && t < 128) ? cur[t - off] : 0;
        __syncthreads();
        if (t < 128) cur[t] += u;
        __syncthreads();
    }
    if (t < 128) {
        int ex = cur[t] - cnt[t];
        int pos = obase + ex;
        cur[t] = pos;
        if (t < nr) row_ptr[r0 + t] = pos;
    }
    if (b == NBK - 1 && t == 128) row_ptr[N] = bbase[NBK];
    __syncthreads();
    for (int i = slab + t; i < send; i += 256) {
        int2 v = tmp[i];
        int rl = v.x >> 16;
        int c = v.x & 0xffff;
        int pos = atomicAdd(&cur[rl], 1);
        epack[pos] = make_int2(c, v.y);
    }
}

// ---------------- bf16 MFMA GEMM (layer GEMMs 2,3) ----------------
__global__ __launch_bounds__(256, 3)
void mfma_gemm(const __hip_bfloat16* __restrict__ A, int lda,
               const __hip_bfloat16* __restrict__ pW,
               __hip_bfloat16* __restrict__ C, int M) {
    __shared__ unsigned short As[64][136];
    const int tid = threadIdx.x;
    const int wave = tid >> 6;
    const int lane = tid & 63;
    const int ln15 = lane & 15;
    const int quad = lane >> 4;
    const int m0 = blockIdx.x * 64;
    const int ntw = wave * 2;

    f32x4 acc[4][2];
#pragma unroll
    for (int s = 0; s < 4; ++s)
#pragma unroll
        for (int h = 0; h < 2; ++h) acc[s][h] = (f32x4){0.f, 0.f, 0.f, 0.f};

#pragma unroll
    for (int i = 0; i < 4; ++i) {
        int idx = tid + i * 256;
        int r = idx >> 4;
        int c8 = (idx & 15) * 8;
        uint4 v = *(const uint4*)&A[(size_t)(m0 + r) * lda + c8];
        *(uint4*)&As[r][c8] = v;
    }
    __syncthreads();
#pragma unroll
    for (int kc = 0; kc < 4; ++kc) {
        short8 af[4];
#pragma unroll
        for (int s = 0; s < 4; ++s)
            af[s] = *(const short8*)&As[s * 16 + ln15][kc * 32 + quad * 8];
        short8 bf[2];
#pragma unroll
        for (int h = 0; h < 2; ++h)
            bf[h] = *(const short8*)&pW[((size_t)((ntw + h) * 4 + kc) * 64 + lane) * 8];
#pragma unroll
        for (int s = 0; s < 4; ++s)
#pragma unroll
            for (int h = 0; h < 2; ++h)
                acc[s][h] = __builtin_amdgcn_mfma_f32_16x16x32_bf16(
                    af[s], bf[h], acc[s][h], 0, 0, 0);
    }

#pragma unroll
    for (int s = 0; s < 4; ++s)
#pragma unroll
        for (int h = 0; h < 2; ++h) {
            int cl = (ntw + h) * 16 + ln15;
#pragma unroll
            for (int r = 0; r < 4; ++r) {
                int rw = m0 + s * 16 + quad * 4 + r;
                if (rw < M)
                    C[(size_t)rw * 128 + cl] = __float2bfloat16(acc[s][h][r]);
            }
        }
}

// ---------------- SpMM: 1 node/wave, x8 outstanding gathers ----------------
__global__ __launch_bounds__(256)
void spmm_kernel(const int* __restrict__ row_ptr, const int2* __restrict__ epack,
                 const __hip_bfloat16* __restrict__ support,
                 const float* __restrict__ bias, __hip_bfloat16* __restrict__ out,
                 int ldo, int n) {
    int wv = threadIdx.x >> 6;
    int l = threadIdx.x & 63;
    int node = blockIdx.x * 4 + wv;
    if (node >= n) return;
    const long long* ep = (const long long*)epack;
    int start = row_ptr[node], end = row_ptr[node + 1];
    float ax = 0.f, ay = 0.f;
    int p = start;
    for (; p + 8 <= end; p += 8) {
        long long v[8];
        ushort2 u[8];
#pragma unroll
        for (int j = 0; j < 8; ++j) v[j] = ep[p + j];
#pragma unroll
        for (int j = 0; j < 8; ++j)
            u[j] = *(const ushort2*)&support[(size_t)(unsigned int)(v[j] & 0xffffffff) * 128 + l * 2];
#pragma unroll
        for (int j = 0; j < 8; ++j) {
            float f = __int_as_float((int)(v[j] >> 32));
            ax += f * b2f(u[j].x);
            ay += f * b2f(u[j].y);
        }
    }
    for (; p < end; ++p) {
        long long v0 = ep[p];
        ushort2 u0 = *(const ushort2*)&support[(size_t)(unsigned int)(v0 & 0xffffffff) * 128 + l * 2];
        float f0 = __int_as_float((int)(v0 >> 32));
        ax += f0 * b2f(u0.x);
        ay += f0 * b2f(u0.y);
    }
    unsigned int packed = (unsigned int)f2bb(fmaxf(ax + bias[l * 2 + 0], 0.f))
                        | ((unsigned int)f2bb(fmaxf(ay + bias[l * 2 + 1], 0.f)) << 16);
    __builtin_nontemporal_store(packed, (unsigned int*)&out[(size_t)node * ldo + l * 2]);
}

// ---------------- fused FC head ----------------
__global__ __launch_bounds__(256, 3)
void fc123_kernel(const __hip_bfloat16* __restrict__ featb,
                  const __hip_bfloat16* __restrict__ pfcW1,
                  const float* __restrict__ fcb1,
                  const __hip_bfloat16* __restrict__ pfcW2,
                  const float* __restrict__ fcb2,
                  const float* __restrict__ fcW3, const float* __restrict__ fcb3,
                  float* __restrict__ out, int M) {
    __shared__ unsigned short As[64][136];
    __shared__ float w3s[128];
    __shared__ float b3s[2];
    const int tid = threadIdx.x;
    const int wave = tid >> 6;
    const int lane = tid & 63;
    const int ln15 = lane & 15;
    const int quad = lane >> 4;
    const int m0 = blockIdx.x * 64;
    if (tid < 128) w3s[tid] = fcW3[tid];
    if (tid < 2) b3s[tid] = fcb3[tid];

    f32x4 acc[4][2];
#pragma unroll
    for (int s = 0; s < 4; ++s)
#pragma unroll
        for (int h = 0; h < 2; ++h) acc[s][h] = (f32x4){0.f, 0.f, 0.f, 0.f};
    for (int kb = 0; kb < 3; ++kb) {
#pragma unroll
        for (int i = 0; i < 4; ++i) {
            int idx = tid + i * 256;
            int r = idx >> 4;
            int c8 = (idx & 15) * 8;
            uint4 v = *(const uint4*)&featb[(size_t)(m0 + r) * 384 + kb * 128 + c8];
            *(uint4*)&As[r][c8] = v;
        }
        __syncthreads();
#pragma unroll
        for (int kc = 0; kc < 4; ++kc) {
            short8 af[4];
#pragma unroll
            for (int s = 0; s < 4; ++s)
                af[s] = *(const short8*)&As[s * 16 + ln15][kc * 32 + quad * 8];
            short8 bf[2];
#pragma unroll
            for (int h = 0; h < 2; ++h) {
                int kcg = kb * 4 + kc;
                bf[h] = *(const short8*)&pfcW1[((size_t)((wave * 2 + h) * 12 + kcg) * 64 + lane) * 8];
            }
#pragma unroll
            for (int s = 0; s < 4; ++s)
#pragma unroll
                for (int h = 0; h < 2; ++h)
                    acc[s][h] = __builtin_amdgcn_mfma_f32_16x16x32_bf16(
                        af[s], bf[h], acc[s][h], 0, 0, 0);
        }
        __syncthreads();
    }
#pragma unroll
    for (int s = 0; s < 4; ++s)
#pragma unroll
        for (int h = 0; h < 2; ++h) {
            int col = (wave * 2 + h) * 16 + ln15;
            float bv = fcb1[col];
#pragma unroll
            for (int r = 0; r < 4; ++r) {
                int row = s * 16 + quad * 4 + r;
                As[row][col] = f2bb(fmaxf(acc[s][h][r] + bv, 0.f));
            }
        }
    __syncthreads();

    f32x4 acc2[4];
#pragma unroll
    for (int s = 0; s < 4; ++s) acc2[s] = (f32x4){0.f, 0.f, 0.f, 0.f};
#pragma unroll
    for (int kc = 0; kc < 4; ++kc) {
        short8 af[4];
#pragma unroll
        for (int s = 0; s < 4; ++s)
            af[s] = *(const short8*)&As[s * 16 + ln15][kc * 32 + quad * 8];
        short8 bfw = *(const short8*)&pfcW2[((size_t)(wave * 4 + kc) * 64 + lane) * 8];
#pragma unroll
        for (int s = 0; s < 4; ++s)
            acc2[s] = __builtin_amdgcn_mfma_f32_16x16x32_bf16(af[s], bfw, acc2[s], 0, 0, 0);
    }
    __syncthreads();
    {
        int col2 = wave * 16 + ln15;
        float bv = fcb2[col2];
#pragma unroll
        for (int s = 0; s < 4; ++s)
#pragma unroll
            for (int r = 0; r < 4; ++r) {
                int row = s * 16 + quad * 4 + r;
                As[row][col2] = f2bb(fmaxf(acc2[s][r] + bv, 0.f));
            }
    }
    __syncthreads();

    if (tid < 128) {
        int row = tid >> 1, cls = tid & 1;
        int grow = m0 + row;
        if (grow < M) {
            float a = b3s[cls];
#pragma unroll
            for (int k = 0; k < 64; ++k)
                a += b2f(As[row][k]) * w3s[k * 2 + cls];
            out[(size_t)grow * 2 + cls] = a;
        }
    }
}

extern "C" void kernel_launch(void* const* d_in, const int* in_sizes, int n_in,
                              void* d_out, int out_size, void* d_ws, size_t ws_size,
                              hipStream_t stream) {
    const int*   adj_row  = (const int*)d_in[0];
    const int*   adj_col  = (const int*)d_in[1];
    const float* adj_vals = (const float*)d_in[2];
    const float* x        = (const float*)d_in[3];
    const float* W1   = (const float*)d_in[5];
    const float* b1   = (const float*)d_in[6];
    const float* W2   = (const float*)d_in[7];
    const float* b2   = (const float*)d_in[8];
    const float* W3   = (const float*)d_in[9];
    const float* b3   = (const float*)d_in[10];
    const float* fcW1 = (const float*)d_in[11];
    const float* fcb1 = (const float*)d_in[12];
    const float* fcW2 = (const float*)d_in[13];
    const float* fcb2 = (const float*)d_in[14];
    const float* fcW3 = (const float*)d_in[15];
    const float* fcb3 = (const float*)d_in[16];
    float* out = (float*)d_out;

    const int N = N_NODES, E = N_EDGES;
    const int Mpad = 50048;

    char* p = (char*)d_ws;
    auto alloc = [&](size_t bytes) {
        char* q = p;
        p += (bytes + 255) & ~(size_t)255;
        return q;
    };
    __hip_bfloat16* featb    = (__hip_bfloat16*)alloc((size_t)Mpad * 384 * 2); // g1|g2|g3
    __hip_bfloat16* supportb = (__hip_bfloat16*)alloc((size_t)Mpad * 128 * 2);
    __hip_bfloat16* pW2   = (__hip_bfloat16*)alloc(16384 * 2);
    __hip_bfloat16* pW3   = (__hip_bfloat16*)alloc(16384 * 2);
    __hip_bfloat16* pfcW1 = (__hip_bfloat16*)alloc(49152 * 2);
    __hip_bfloat16* pfcW2 = (__hip_bfloat16*)alloc(8192 * 2);
    int*   row_ptr   = (int*)alloc((size_t)(N + 1) * 4);
    int*   bbase     = (int*)alloc((size_t)(NBK + 1) * 4);
    int*   bcursor   = (int*)alloc((size_t)NBK * 4);
    int2*  epack     = (int2*)alloc((size_t)E * 8);
    int2*  tmp       = (int2*)alloc((size_t)NBK * BCAP * 8);

    // ---- stage1: binA + gemm1 + weight packs in one launch ----
    hipMemsetAsync(bcursor, 0, (size_t)NBK * 4, stream);
    stage1_kernel<<<1022, 256, 0, stream>>>(adj_row, adj_col, adj_vals, bcursor, tmp, E,
                                            x, supportb, N,
                                            W1, W2, W3, fcW1, fcW2,
                                            pW2, pW3, pfcW1, pfcW2);
    bscan_kernel<<<1, 512, 0, stream>>>(bcursor, bbase);
    binB_kernel<<<NBK, 256, 0, stream>>>(tmp, bcursor, bbase, row_ptr, epack, N);

    const int gemmGrid = cdiv(N, 64);
    const int spmmGrid = cdiv(N, 4);

    // ---- GCN layer 1 aggregate ----
    spmm_kernel<<<spmmGrid, 256, 0, stream>>>(row_ptr, epack, supportb, b1,
                                              featb + 0, 384, N);
    // ---- GCN layer 2 ----
    mfma_gemm<<<gemmGrid, 256, 0, stream>>>(featb + 0, 384, pW2, supportb, N);
    spmm_kernel<<<spmmGrid, 256, 0, stream>>>(row_ptr, epack, supportb, b2,
                                              featb + 128, 384, N);
    // ---- GCN layer 3 ----
    mfma_gemm<<<gemmGrid, 256, 0, stream>>>(featb + 128, 384, pW3, supportb, N);
    spmm_kernel<<<spmmGrid, 256, 0, stream>>>(row_ptr, epack, supportb, b3,
                                              featb + 256, 384, N);

    // ---- fused FC head ----
    fc123_kernel<<<gemmGrid, 256, 0, stream>>>(featb, pfcW1, fcb1, pfcW2, fcb2,
                                               fcW3, fcb3, out, N);
}

// Round 13
// 279.201 us; speedup vs baseline: 1.4718x; 1.0617x over previous
//
#include <hip/hip_runtime.h>
#include <hip/hip_bf16.h>

#define N_NODES 50000
#define N_EDGES 800000
#define NBK 391          // ceil(50000/128) row buckets of 128 rows
#define BCAP 2560        // slab capacity per bucket (mean 2048 + 11 sigma)
#define PADSLACK 896     // max pad per bucket: 128 rows x 7

static inline int cdiv(int a, int b) { return (a + b - 1) / b; }

typedef __attribute__((ext_vector_type(8))) short short8;
typedef __attribute__((ext_vector_type(4))) float f32x4;

__device__ __forceinline__ float b2f(unsigned short u) {
    union { unsigned int i; float f; } c;
    c.i = ((unsigned int)u) << 16;
    return c.f;
}
__device__ __forceinline__ unsigned short f2bb(float f) {
    __hip_bfloat16 h = __float2bfloat16(f);
    return *(unsigned short*)&h;
}

__device__ __forceinline__ void pack_one(const float* __restrict__ W,
                                         __hip_bfloat16* __restrict__ out,
                                         int K, int N, int t) {
    int lane = t & 63;
    int kc = (t >> 6) % (K / 32);
    int nt = (t >> 6) / (K / 32);
    int kbase = kc * 32 + (lane >> 4) * 8;
    int col = nt * 16 + (lane & 15);
    __hip_bfloat16* dst = out + (size_t)t * 8;
#pragma unroll
    for (int j = 0; j < 8; ++j)
        dst[j] = __float2bfloat16(W[(size_t)(kbase + j) * N + col]);
}

// ---------------- stage1: binA (0..195) + gemm1 (196..977) + packs (978..1021) ----------------
__global__ __launch_bounds__(256)
void stage1_kernel(const int* __restrict__ row, const int* __restrict__ col,
                   const float* __restrict__ vals, int* __restrict__ bcursor,
                   int2* __restrict__ tmp, int E,
                   const float* __restrict__ x, __hip_bfloat16* __restrict__ support,
                   int M,
                   const float* __restrict__ W1, const float* __restrict__ W2,
                   const float* __restrict__ W3, const float* __restrict__ fcW1,
                   const float* __restrict__ fcW2,
                   __hip_bfloat16* __restrict__ pW2, __hip_bfloat16* __restrict__ pW3,
                   __hip_bfloat16* __restrict__ pfcW1, __hip_bfloat16* __restrict__ pfcW2) {
    __shared__ unsigned short As[64][136];
    __shared__ int hist[NBK];
    __shared__ int base[NBK];
    const int b = blockIdx.x;
    const int tid = threadIdx.x;

    if (b < 196) {
        const int CH = 4096;
        int e0 = b * CH;
        for (int i = tid; i < NBK; i += 256) hist[i] = 0;
        __syncthreads();
        for (int i = tid; i < CH; i += 256) {
            int e = e0 + i;
            if (e < E) atomicAdd(&hist[row[e] >> 7], 1);
        }
        __syncthreads();
        for (int i = tid; i < NBK; i += 256) {
            int c = hist[i];
            base[i] = (c > 0) ? (i * BCAP + atomicAdd(&bcursor[i], c)) : 0;
            hist[i] = 0;
        }
        __syncthreads();
        for (int i = tid; i < CH; i += 256) {
            int e = e0 + i;
            if (e < E) {
                int r = row[e];
                int bk = r >> 7;
                int rk = atomicAdd(&hist[bk], 1);
                tmp[base[bk] + rk] = make_int2(((r & 127) << 16) | col[e],
                                               __float_as_int(vals[e]));
            }
        }
        return;
    }

    if (b < 978) {
        const int wave = tid >> 6;
        const int lane = tid & 63;
        const int ln15 = lane & 15;
        const int quad = lane >> 4;
        const int m0 = (b - 196) * 64;

        short8 bfr[4][2];
#pragma unroll
        for (int kc = 0; kc < 4; ++kc)
#pragma unroll
            for (int h = 0; h < 2; ++h)
#pragma unroll
                for (int j = 0; j < 8; ++j)
                    bfr[kc][h][j] = (short)f2bb(
                        W1[(size_t)(kc * 32 + quad * 8 + j) * 128 + (wave * 2 + h) * 16 + ln15]);

#pragma unroll
        for (int i = 0; i < 4; ++i) {
            int idx = tid + i * 256;
            int r = idx >> 4;
            int c8 = (idx & 15) * 8;
            uint4 pk = {0, 0, 0, 0};
            if (m0 + r < M) {
                const float* src = &x[(size_t)(m0 + r) * 128 + c8];
                float4 a = *(const float4*)src;
                float4 bq = *(const float4*)(src + 4);
                pk.x = f2bb(a.x) | ((unsigned int)f2bb(a.y) << 16);
                pk.y = f2bb(a.z) | ((unsigned int)f2bb(a.w) << 16);
                pk.z = f2bb(bq.x) | ((unsigned int)f2bb(bq.y) << 16);
                pk.w = f2bb(bq.z) | ((unsigned int)f2bb(bq.w) << 16);
            }
            *(uint4*)&As[r][c8] = pk;
        }
        __syncthreads();

        f32x4 acc[4][2];
#pragma unroll
        for (int s = 0; s < 4; ++s)
#pragma unroll
            for (int h = 0; h < 2; ++h) acc[s][h] = (f32x4){0.f, 0.f, 0.f, 0.f};
#pragma unroll
        for (int kc = 0; kc < 4; ++kc) {
            short8 af[4];
#pragma unroll
            for (int s = 0; s < 4; ++s)
                af[s] = *(const short8*)&As[s * 16 + ln15][kc * 32 + quad * 8];
#pragma unroll
            for (int s = 0; s < 4; ++s)
#pragma unroll
                for (int h = 0; h < 2; ++h)
                    acc[s][h] = __builtin_amdgcn_mfma_f32_16x16x32_bf16(
                        af[s], bfr[kc][h], acc[s][h], 0, 0, 0);
        }
#pragma unroll
        for (int s = 0; s < 4; ++s)
#pragma unroll
            for (int h = 0; h < 2; ++h) {
                int cl = (wave * 2 + h) * 16 + ln15;
#pragma unroll
                for (int r = 0; r < 4; ++r) {
                    int rw = m0 + s * 16 + quad * 4 + r;
                    if (rw < M)
                        support[(size_t)rw * 128 + cl] = __float2bfloat16(acc[s][h][r]);
                }
            }
        return;
    }

    int pb = b - 978;
    if (pb < 8)       pack_one(W2,  pW2,  128, 128, pb * 256 + tid);
    else if (pb < 16) pack_one(W3,  pW3,  128, 128, (pb - 8) * 256 + tid);
    else if (pb < 40) pack_one(fcW1, pfcW1, 384, 128, (pb - 16) * 256 + tid);
    else              pack_one(fcW2, pfcW2, 128, 64, (pb - 40) * 256 + tid);
}

// ---------------- CSR: bucket scan + per-bucket counting sort w/ 8-padding ----------------

__global__ __launch_bounds__(512)
void bscan_kernel(const int* __restrict__ bcursor, int* __restrict__ bbase) {
    __shared__ int s[512];
    int t = threadIdx.x;
    int v = (t < NBK) ? bcursor[t] : 0;
    s[t] = v;
    __syncthreads();
    for (int off = 1; off < 512; off <<= 1) {
        int u = (t >= off) ? s[t - off] : 0;
        __syncthreads();
        s[t] += u;
        __syncthreads();
    }
    if (t < NBK) bbase[t] = s[t] - v;
    if (t == NBK - 1) bbase[NBK] = s[t];
}

// Emits per-row [row_ptr, row_end) with row size padded to a multiple of 8;
// pad entries (col=0,val=0) contribute nothing and gather an L2-hot line.
__global__ __launch_bounds__(256)
void binB_kernel(const int2* __restrict__ tmp, const int* __restrict__ bcursor,
                 const int* __restrict__ bbase, int* __restrict__ row_ptr,
                 int* __restrict__ row_end, int2* __restrict__ epack, int N) {
    int b = blockIdx.x;
    int r0 = b << 7;
    int nr = N - r0; if (nr > 128) nr = 128;
    __shared__ int cnt[128];
    __shared__ int cur[128];
    __shared__ int rpos[128];
    int t = threadIdx.x;
    if (t < 128) cnt[t] = 0;
    __syncthreads();
    int slab = b * BCAP;
    int send = slab + bcursor[b];
    for (int i = slab + t; i < send; i += 256)
        atomicAdd(&cnt[tmp[i].x >> 16], 1);
    __syncthreads();
    int rcnt = (t < 128) ? cnt[t] : 0;
    int pc = (rcnt + 7) & ~7;
    if (t < 128) cur[t] = pc;
    __syncthreads();
    for (int off = 1; off < 128; off <<= 1) {
        int u = (t >= off && t < 128) ? cur[t - off] : 0;
        __syncthreads();
        if (t < 128) cur[t] += u;
        __syncthreads();
    }
    int obase = bbase[b] + b * PADSLACK;
    if (t < 128) {
        int pos = obase + cur[t] - pc;
        rpos[t] = pos;
        cur[t] = pos;
        if (t < nr) {
            row_ptr[r0 + t] = pos;
            row_end[r0 + t] = pos + pc;
        }
    }
    __syncthreads();
    for (int i = slab + t; i < send; i += 256) {
        int2 v = tmp[i];
        int rl = v.x >> 16;
        int c = v.x & 0xffff;
        int pos = atomicAdd(&cur[rl], 1);
        epack[pos] = make_int2(c, v.y);
    }
    if (t < 128) {
        int pos = rpos[t];
#pragma unroll 1
        for (int i = pos + rcnt; i < pos + pc; ++i)
            epack[i] = make_int2(0, 0);
    }
}

// ---------------- bf16 MFMA GEMM (layer GEMMs 2,3) ----------------
__global__ __launch_bounds__(256, 3)
void mfma_gemm(const __hip_bfloat16* __restrict__ A, int lda,
               const __hip_bfloat16* __restrict__ pW,
               __hip_bfloat16* __restrict__ C, int M) {
    __shared__ unsigned short As[64][136];
    const int tid = threadIdx.x;
    const int wave = tid >> 6;
    const int lane = tid & 63;
    const int ln15 = lane & 15;
    const int quad = lane >> 4;
    const int m0 = blockIdx.x * 64;
    const int ntw = wave * 2;

    f32x4 acc[4][2];
#pragma unroll
    for (int s = 0; s < 4; ++s)
#pragma unroll
        for (int h = 0; h < 2; ++h) acc[s][h] = (f32x4){0.f, 0.f, 0.f, 0.f};

#pragma unroll
    for (int i = 0; i < 4; ++i) {
        int idx = tid + i * 256;
        int r = idx >> 4;
        int c8 = (idx & 15) * 8;
        uint4 v = *(const uint4*)&A[(size_t)(m0 + r) * lda + c8];
        *(uint4*)&As[r][c8] = v;
    }
    __syncthreads();
#pragma unroll
    for (int kc = 0; kc < 4; ++kc) {
        short8 af[4];
#pragma unroll
        for (int s = 0; s < 4; ++s)
            af[s] = *(const short8*)&As[s * 16 + ln15][kc * 32 + quad * 8];
        short8 bf[2];
#pragma unroll
        for (int h = 0; h < 2; ++h)
            bf[h] = *(const short8*)&pW[((size_t)((ntw + h) * 4 + kc) * 64 + lane) * 8];
#pragma unroll
        for (int s = 0; s < 4; ++s)
#pragma unroll
            for (int h = 0; h < 2; ++h)
                acc[s][h] = __builtin_amdgcn_mfma_f32_16x16x32_bf16(
                    af[s], bf[h], acc[s][h], 0, 0, 0);
    }

#pragma unroll
    for (int s = 0; s < 4; ++s)
#pragma unroll
        for (int h = 0; h < 2; ++h) {
            int cl = (ntw + h) * 16 + ln15;
#pragma unroll
            for (int r = 0; r < 4; ++r) {
                int rw = m0 + s * 16 + quad * 4 + r;
                if (rw < M)
                    C[(size_t)rw * 128 + cl] = __float2bfloat16(acc[s][h][r]);
            }
        }
}

// ---------------- SpMM: 1 node/wave, pipelined 2x8 outstanding gathers ----------------
__global__ __launch_bounds__(256)
void spmm_kernel(const int* __restrict__ row_ptr, const int* __restrict__ row_end,
                 const int2* __restrict__ epack,
                 const __hip_bfloat16* __restrict__ support,
                 const float* __restrict__ bias, __hip_bfloat16* __restrict__ out,
                 int ldo, int n) {
    int wv = threadIdx.x >> 6;
    int l = threadIdx.x & 63;
    int node = blockIdx.x * 4 + wv;
    if (node >= n) return;
    const long long* ep = (const long long*)epack;
    int p = row_ptr[node], end = row_end[node];
    float ax = 0.f, ay = 0.f;
    long long v[8];
    ushort2 u[8];
    bool have = false;
    if (p < end) {
#pragma unroll
        for (int j = 0; j < 8; ++j) v[j] = ep[p + j];
#pragma unroll
        for (int j = 0; j < 8; ++j)
            u[j] = *(const ushort2*)&support[(size_t)(unsigned int)(v[j] & 0xffffffffu) * 128 + l * 2];
        p += 8;
        have = true;
    }
    while (p < end) {
        long long v2[8];
        ushort2 u2[8];
#pragma unroll
        for (int j = 0; j < 8; ++j) v2[j] = ep[p + j];
#pragma unroll
        for (int j = 0; j < 8; ++j)
            u2[j] = *(const ushort2*)&support[(size_t)(unsigned int)(v2[j] & 0xffffffffu) * 128 + l * 2];
        // accumulate previous batch while new gathers are in flight
#pragma unroll
        for (int j = 0; j < 8; ++j) {
            float f = __int_as_float((int)(v[j] >> 32));
            ax += f * b2f(u[j].x);
            ay += f * b2f(u[j].y);
        }
#pragma unroll
        for (int j = 0; j < 8; ++j) { v[j] = v2[j]; u[j] = u2[j]; }
        p += 8;
    }
    if (have) {
#pragma unroll
        for (int j = 0; j < 8; ++j) {
            float f = __int_as_float((int)(v[j] >> 32));
            ax += f * b2f(u[j].x);
            ay += f * b2f(u[j].y);
        }
    }
    unsigned int packed = (unsigned int)f2bb(fmaxf(ax + bias[l * 2 + 0], 0.f))
                        | ((unsigned int)f2bb(fmaxf(ay + bias[l * 2 + 1], 0.f)) << 16);
    __builtin_nontemporal_store(packed, (unsigned int*)&out[(size_t)node * ldo + l * 2]);
}

// ---------------- fused FC head ----------------
__global__ __launch_bounds__(256, 3)
void fc123_kernel(const __hip_bfloat16* __restrict__ featb,
                  const __hip_bfloat16* __restrict__ pfcW1,
                  const float* __restrict__ fcb1,
                  const __hip_bfloat16* __restrict__ pfcW2,
                  const float* __restrict__ fcb2,
                  const float* __restrict__ fcW3, const float* __restrict__ fcb3,
                  float* __restrict__ out, int M) {
    __shared__ unsigned short As[64][136];
    __shared__ float w3s[128];
    __shared__ float b3s[2];
    const int tid = threadIdx.x;
    const int wave = tid >> 6;
    const int lane = tid & 63;
    const int ln15 = lane & 15;
    const int quad = lane >> 4;
    const int m0 = blockIdx.x * 64;
    if (tid < 128) w3s[tid] = fcW3[tid];
    if (tid < 2) b3s[tid] = fcb3[tid];

    f32x4 acc[4][2];
#pragma unroll
    for (int s = 0; s < 4; ++s)
#pragma unroll
        for (int h = 0; h < 2; ++h) acc[s][h] = (f32x4){0.f, 0.f, 0.f, 0.f};
    for (int kb = 0; kb < 3; ++kb) {
#pragma unroll
        for (int i = 0; i < 4; ++i) {
            int idx = tid + i * 256;
            int r = idx >> 4;
            int c8 = (idx & 15) * 8;
            uint4 v = *(const uint4*)&featb[(size_t)(m0 + r) * 384 + kb * 128 + c8];
            *(uint4*)&As[r][c8] = v;
        }
        __syncthreads();
#pragma unroll
        for (int kc = 0; kc < 4; ++kc) {
            short8 af[4];
#pragma unroll
            for (int s = 0; s < 4; ++s)
                af[s] = *(const short8*)&As[s * 16 + ln15][kc * 32 + quad * 8];
            short8 bf[2];
#pragma unroll
            for (int h = 0; h < 2; ++h) {
                int kcg = kb * 4 + kc;
                bf[h] = *(const short8*)&pfcW1[((size_t)((wave * 2 + h) * 12 + kcg) * 64 + lane) * 8];
            }
#pragma unroll
            for (int s = 0; s < 4; ++s)
#pragma unroll
                for (int h = 0; h < 2; ++h)
                    acc[s][h] = __builtin_amdgcn_mfma_f32_16x16x32_bf16(
                        af[s], bf[h], acc[s][h], 0, 0, 0);
        }
        __syncthreads();
    }
#pragma unroll
    for (int s = 0; s < 4; ++s)
#pragma unroll
        for (int h = 0; h < 2; ++h) {
            int col = (wave * 2 + h) * 16 + ln15;
            float bv = fcb1[col];
#pragma unroll
            for (int r = 0; r < 4; ++r) {
                int row = s * 16 + quad * 4 + r;
                As[row][col] = f2bb(fmaxf(acc[s][h][r] + bv, 0.f));
            }
        }
    __syncthreads();

    f32x4 acc2[4];
#pragma unroll
    for (int s = 0; s < 4; ++s) acc2[s] = (f32x4){0.f, 0.f, 0.f, 0.f};
#pragma unroll
    for (int kc = 0; kc < 4; ++kc) {
        short8 af[4];
#pragma unroll
        for (int s = 0; s < 4; ++s)
            af[s] = *(const short8*)&As[s * 16 + ln15][kc * 32 + quad * 8];
        short8 bfw = *(const short8*)&pfcW2[((size_t)(wave * 4 + kc) * 64 + lane) * 8];
#pragma unroll
        for (int s = 0; s < 4; ++s)
            acc2[s] = __builtin_amdgcn_mfma_f32_16x16x32_bf16(af[s], bfw, acc2[s], 0, 0, 0);
    }
    __syncthreads();
    {
        int col2 = wave * 16 + ln15;
        float bv = fcb2[col2];
#pragma unroll
        for (int s = 0; s < 4; ++s)
#pragma unroll
            for (int r = 0; r < 4; ++r) {
                int row = s * 16 + quad * 4 + r;
                As[row][col2] = f2bb(fmaxf(acc2[s][r] + bv, 0.f));
            }
    }
    __syncthreads();

    if (tid < 128) {
        int row = tid >> 1, cls = tid & 1;
        int grow = m0 + row;
        if (grow < M) {
            float a = b3s[cls];
#pragma unroll
            for (int k = 0; k < 64; ++k)
                a += b2f(As[row][k]) * w3s[k * 2 + cls];
            out[(size_t)grow * 2 + cls] = a;
        }
    }
}

extern "C" void kernel_launch(void* const* d_in, const int* in_sizes, int n_in,
                              void* d_out, int out_size, void* d_ws, size_t ws_size,
                              hipStream_t stream) {
    const int*   adj_row  = (const int*)d_in[0];
    const int*   adj_col  = (const int*)d_in[1];
    const float* adj_vals = (const float*)d_in[2];
    const float* x        = (const float*)d_in[3];
    const float* W1   = (const float*)d_in[5];
    const float* b1   = (const float*)d_in[6];
    const float* W2   = (const float*)d_in[7];
    const float* b2   = (const float*)d_in[8];
    const float* W3   = (const float*)d_in[9];
    const float* b3   = (const float*)d_in[10];
    const float* fcW1 = (const float*)d_in[11];
    const float* fcb1 = (const float*)d_in[12];
    const float* fcW2 = (const float*)d_in[13];
    const float* fcb2 = (const float*)d_in[14];
    const float* fcW3 = (const float*)d_in[15];
    const float* fcb3 = (const float*)d_in[16];
    float* out = (float*)d_out;

    const int N = N_NODES, E = N_EDGES;
    const int Mpad = 50048;
    const int EPAD = E + NBK * PADSLACK + 64;   // padded edge capacity

    char* p = (char*)d_ws;
    auto alloc = [&](size_t bytes) {
        char* q = p;
        p += (bytes + 255) & ~(size_t)255;
        return q;
    };
    __hip_bfloat16* featb    = (__hip_bfloat16*)alloc((size_t)Mpad * 384 * 2); // g1|g2|g3
    __hip_bfloat16* supportb = (__hip_bfloat16*)alloc((size_t)Mpad * 128 * 2);
    __hip_bfloat16* pW2   = (__hip_bfloat16*)alloc(16384 * 2);
    __hip_bfloat16* pW3   = (__hip_bfloat16*)alloc(16384 * 2);
    __hip_bfloat16* pfcW1 = (__hip_bfloat16*)alloc(49152 * 2);
    __hip_bfloat16* pfcW2 = (__hip_bfloat16*)alloc(8192 * 2);
    int*   row_ptr   = (int*)alloc((size_t)(N + 1) * 4);
    int*   row_end   = (int*)alloc((size_t)(N + 1) * 4);
    int*   bbase     = (int*)alloc((size_t)(NBK + 1) * 4);
    int*   bcursor   = (int*)alloc((size_t)NBK * 4);
    int2*  epack     = (int2*)alloc((size_t)EPAD * 8);
    int2*  tmp       = (int2*)alloc((size_t)NBK * BCAP * 8);

    // ---- stage1: binA + gemm1 + weight packs in one launch ----
    hipMemsetAsync(bcursor, 0, (size_t)NBK * 4, stream);
    stage1_kernel<<<1022, 256, 0, stream>>>(adj_row, adj_col, adj_vals, bcursor, tmp, E,
                                            x, supportb, N,
                                            W1, W2, W3, fcW1, fcW2,
                                            pW2, pW3, pfcW1, pfcW2);
    bscan_kernel<<<1, 512, 0, stream>>>(bcursor, bbase);
    binB_kernel<<<NBK, 256, 0, stream>>>(tmp, bcursor, bbase, row_ptr, row_end, epack, N);

    const int gemmGrid = cdiv(N, 64);
    const int spmmGrid = cdiv(N, 4);

    // ---- GCN layer 1 aggregate ----
    spmm_kernel<<<spmmGrid, 256, 0, stream>>>(row_ptr, row_end, epack, supportb, b1,
                                              featb + 0, 384, N);
    // ---- GCN layer 2 ----
    mfma_gemm<<<gemmGrid, 256, 0, stream>>>(featb + 0, 384, pW2, supportb, N);
    spmm_kernel<<<spmmGrid, 256, 0, stream>>>(row_ptr, row_end, epack, supportb, b2,
                                              featb + 128, 384, N);
    // ---- GCN layer 3 ----
    mfma_gemm<<<gemmGrid, 256, 0, stream>>>(featb + 128, 384, pW3, supportb, N);
    spmm_kernel<<<spmmGrid, 256, 0, stream>>>(row_ptr, row_end, epack, supportb, b3,
                                              featb + 256, 384, N);

    // ---- fused FC head ----
    fc123_kernel<<<gemmGrid, 256, 0, stream>>>(featb, pfcW1, fcb1, pfcW2, fcb2,
                                               fcW3, fcb3, out, N);
}